// Round 1
// baseline (399.044 us; speedup 1.0000x reference)
//
#include <hip/hip_runtime.h>
#include <hip/hip_bf16.h>
#include <stdint.h>

// EmbeddingDropout: out[b,s,:] = W[words[b,s],:] * keep[words[b,s]]
// keep[v] derived from JAX threefry2x32, key=42, partitionable path:
//   bits[v] = y0 ^ y1 where (y0,y1) = threefry2x32(k=(0,42), ctr=(0, v))
//   u = bitcast_f32((bits>>9)|0x3f800000) - 1.0f;  keep = (u>=0.1f) ? 1/0.9f : 0

#define V_SIZE 50257
#define D_SIZE 1024
#define B_SIZE 32
#define S_SIZE 2048

__device__ __forceinline__ void tf_round(uint32_t& x0, uint32_t& x1, int r) {
    x0 += x1;
    x1 = (x1 << r) | (x1 >> (32 - r));
    x1 ^= x0;
}

// Threefry-2x32, 20 rounds, returns y0 ^ y1 (JAX partitionable 32-bit fold)
__device__ __forceinline__ uint32_t threefry2x32_xor(uint32_t k0, uint32_t k1,
                                                     uint32_t c0, uint32_t c1) {
    const uint32_t ks2 = k0 ^ k1 ^ 0x1BD11BDAu;
    uint32_t x0 = c0 + k0;
    uint32_t x1 = c1 + k1;

    tf_round(x0, x1, 13); tf_round(x0, x1, 15); tf_round(x0, x1, 26); tf_round(x0, x1, 6);
    x0 += k1;  x1 += ks2 + 1u;
    tf_round(x0, x1, 17); tf_round(x0, x1, 29); tf_round(x0, x1, 16); tf_round(x0, x1, 24);
    x0 += ks2; x1 += k0 + 2u;
    tf_round(x0, x1, 13); tf_round(x0, x1, 15); tf_round(x0, x1, 26); tf_round(x0, x1, 6);
    x0 += k0;  x1 += k1 + 3u;
    tf_round(x0, x1, 17); tf_round(x0, x1, 29); tf_round(x0, x1, 16); tf_round(x0, x1, 24);
    x0 += k1;  x1 += ks2 + 4u;
    tf_round(x0, x1, 13); tf_round(x0, x1, 15); tf_round(x0, x1, 26); tf_round(x0, x1, 6);
    x0 += ks2; x1 += k0 + 5u;
    return x0 ^ x1;
}

__device__ __forceinline__ float keep_factor(int v) {
    uint32_t bits = threefry2x32_xor(0u, 42u, 0u, (uint32_t)v);
    float u = __uint_as_float((bits >> 9) | 0x3f800000u) - 1.0f;
    return (u >= 0.1f) ? (1.0f / 0.9f) : 0.0f;
}

// One block (256 threads) per token; each thread moves one float4 of the
// D=1024 embedding row (256 * 4 = 1024 floats).
__global__ __launch_bounds__(256)
void EmbeddingDropout_46918222741585_kernel(const int* __restrict__ words,
                                            const float* __restrict__ W,
                                            float* __restrict__ out) {
    const int token = blockIdx.x;               // 0 .. B*S-1
    const int v = words[token];                 // uniform per block -> scalar load
    const float keep = keep_factor(v);

    const float4* __restrict__ src =
        (const float4*)(W + (size_t)v * D_SIZE);
    float4* __restrict__ dst = (float4*)(out + (size_t)token * D_SIZE);

    float4 x = src[threadIdx.x];
    x.x *= keep; x.y *= keep; x.z *= keep; x.w *= keep;
    dst[threadIdx.x] = x;
}

extern "C" void kernel_launch(void* const* d_in, const int* in_sizes, int n_in,
                              void* d_out, int out_size, void* d_ws, size_t ws_size,
                              hipStream_t stream) {
    const int* words = (const int*)d_in[0];     // [B, S] int32
    const float* W   = (const float*)d_in[1];   // [V, D] float32
    float* out       = (float*)d_out;           // [B, S, D] float32

    const int n_tokens = B_SIZE * S_SIZE;       // 65536 blocks
    EmbeddingDropout_46918222741585_kernel<<<n_tokens, 256, 0, stream>>>(words, W, out);
}